// Round 1
// baseline (73.728 us; speedup 1.0000x reference)
//
#include <hip/hip_runtime.h>
#include <math.h>

#define EPSF 1e-8f

constexpr int B = 16;
constexpr int N = 2048;
constexpr int NCHUNK = 4;           // n split across blocks
constexpr int MCHUNK = 4;           // m split across blocks
constexpr int NC = N / NCHUNK;      // 512 n per block
constexpr int MC = N / MCHUNK;      // 512 m per block (2 per thread)
constexpr int THREADS = 256;

__device__ __forceinline__ void quat_to_mat(const float q[4], float R[3][3]) {
    float nrm = sqrtf(q[0]*q[0] + q[1]*q[1] + q[2]*q[2] + q[3]*q[3]);
    nrm = fmaxf(nrm, EPSF);
    float inv = 1.0f / nrm;
    float w = q[0]*inv, x = q[1]*inv, y = q[2]*inv, z = q[3]*inv;
    R[0][0] = 1.0f - 2.0f*(y*y + z*z);
    R[0][1] = 2.0f*(x*y - w*z);
    R[0][2] = 2.0f*(x*z + w*y);
    R[1][0] = 2.0f*(x*y + w*z);
    R[1][1] = 1.0f - 2.0f*(x*x + z*z);
    R[1][2] = 2.0f*(y*z - w*x);
    R[2][0] = 2.0f*(x*z - w*y);
    R[2][1] = 2.0f*(y*z + w*x);
    R[2][2] = 1.0f - 2.0f*(x*x + y*y);
}

// grid: (B, MCHUNK, NCHUNK), block: THREADS
// partial layout: partial[nc*B*N + b*N + m]  (coalesced store & load)
__global__ __launch_bounds__(THREADS)
void quat_main_kernel(const float* __restrict__ predq,
                      const float* __restrict__ gtq,
                      const float* __restrict__ points,
                      float* __restrict__ partial,
                      float* __restrict__ out) {
    const int b  = blockIdx.x;
    const int mc = blockIdx.y;
    const int nc = blockIdx.z;
    const int t  = threadIdx.x;

    __shared__ float4 sp[NC];   // 8 KB

    // ---- quat -> combined rotation M = R_gt^T * R_pred (wave-uniform, cheap) ----
    float pq[4], gq[4];
    #pragma unroll
    for (int i = 0; i < 4; ++i) { pq[i] = predq[4*b + i]; gq[i] = gtq[4*b + i]; }

    float Rp[3][3], Rg[3][3];
    quat_to_mat(pq, Rp);
    quat_to_mat(gq, Rg);

    float M[3][3];
    #pragma unroll
    for (int i = 0; i < 3; ++i)
        #pragma unroll
        for (int j = 0; j < 3; ++j) {
            float s = 0.0f;
            #pragma unroll
            for (int c = 0; c < 3; ++c) s = fmaf(Rg[c][i], Rp[c][j], s);
            M[i][j] = s;
        }

    // ---- cosine loss term (one block per batch contributes) ----
    if (mc == 0 && nc == 0 && t == 0) {
        float dot = pq[0]*gq[0] + pq[1]*gq[1] + pq[2]*gq[2] + pq[3]*gq[3];
        float np_ = sqrtf(pq[0]*pq[0] + pq[1]*pq[1] + pq[2]*pq[2] + pq[3]*pq[3]);
        float ng_ = sqrtf(gq[0]*gq[0] + gq[1]*gq[1] + gq[2]*gq[2] + gq[3]*gq[3]);
        float denom = fmaxf(np_ * ng_, EPSF);
        atomicAdd(out, (1.0f - dot / denom) * (1.0f / (float)B));
    }

    // ---- stage this block's n-chunk into LDS as (px,py,pz,|p|^2) ----
    const float* P = points + (size_t)b * 3 * N;
    const int n0 = nc * NC;
    #pragma unroll
    for (int i = t; i < NC; i += THREADS) {
        float px = P[n0 + i];
        float py = P[N + n0 + i];
        float pz = P[2*N + n0 + i];
        sp[i] = make_float4(px, py, pz, fmaf(px, px, fmaf(py, py, pz*pz)));
    }
    __syncthreads();

    // ---- each thread: 2 m-points ----
    const int m1 = mc * MC + t;
    const int m2 = m1 + THREADS;

    float ax = P[m1], ay = P[N + m1], az = P[2*N + m1];
    float bx = P[m2], by = P[N + m2], bz = P[2*N + m2];

    // n-coeffs = -2 * (M p_m)
    float n1x = -2.0f * (M[0][0]*ax + M[0][1]*ay + M[0][2]*az);
    float n1y = -2.0f * (M[1][0]*ax + M[1][1]*ay + M[1][2]*az);
    float n1z = -2.0f * (M[2][0]*ax + M[2][1]*ay + M[2][2]*az);
    float n2x = -2.0f * (M[0][0]*bx + M[0][1]*by + M[0][2]*bz);
    float n2y = -2.0f * (M[1][0]*bx + M[1][1]*by + M[1][2]*bz);
    float n2z = -2.0f * (M[2][0]*bx + M[2][1]*by + M[2][2]*bz);

    float min1 = 3.4e38f, min2 = 3.4e38f;
    #pragma unroll 8
    for (int n = 0; n < NC; ++n) {
        float4 p = sp[n];
        float d1 = fmaf(p.x, n1x, p.w);
        d1 = fmaf(p.y, n1y, d1);
        d1 = fmaf(p.z, n1z, d1);
        min1 = fminf(min1, d1);
        float d2 = fmaf(p.x, n2x, p.w);
        d2 = fmaf(p.y, n2y, d2);
        d2 = fmaf(p.z, n2z, d2);
        min2 = fminf(min2, d2);
    }

    partial[(size_t)nc * B * N + (size_t)b * N + m1] = min1;
    partial[(size_t)nc * B * N + (size_t)b * N + m2] = min2;
}

// grid: B*N/THREADS = 128 blocks
__global__ __launch_bounds__(THREADS)
void quat_finalize_kernel(const float* __restrict__ points,
                          const float* __restrict__ partial,
                          float* __restrict__ out) {
    const int i = blockIdx.x * THREADS + threadIdx.x;   // 0 .. B*N-1
    const int b = i >> 11;          // / N
    const int m = i & (N - 1);

    float v0 = partial[i];
    float v1 = partial[B*N + i];
    float v2 = partial[2*B*N + i];
    float v3 = partial[3*B*N + i];
    float mn = fminf(fminf(v0, v1), fminf(v2, v3));

    const float* P = points + (size_t)b * 3 * N;
    float px = P[m], py = P[N + m], pz = P[2*N + m];
    float v = mn + fmaf(px, px, fmaf(py, py, pz*pz));

    // wave64 reduce
    #pragma unroll
    for (int o = 32; o > 0; o >>= 1) v += __shfl_down(v, o, 64);

    __shared__ float wsum[THREADS / 64];
    const int lane = threadIdx.x & 63;
    const int wid  = threadIdx.x >> 6;
    if (lane == 0) wsum[wid] = v;
    __syncthreads();
    if (threadIdx.x == 0) {
        float s = wsum[0] + wsum[1] + wsum[2] + wsum[3];
        atomicAdd(out + 1, s * (1.0f / (float)(B * N)));
    }
}

extern "C" void kernel_launch(void* const* d_in, const int* in_sizes, int n_in,
                              void* d_out, int out_size, void* d_ws, size_t ws_size,
                              hipStream_t stream) {
    const float* predq  = (const float*)d_in[0];   // (16,4)
    const float* gtq    = (const float*)d_in[1];   // (16,4)
    const float* points = (const float*)d_in[2];   // (16,3,2048)
    float* out = (float*)d_out;                    // [cos_loss, pt_loss]
    float* partial = (float*)d_ws;                 // NCHUNK * B * N floats = 512 KB

    hipMemsetAsync(d_out, 0, 2 * sizeof(float), stream);

    dim3 grid(B, MCHUNK, NCHUNK);
    quat_main_kernel<<<grid, THREADS, 0, stream>>>(predq, gtq, points, partial, out);

    quat_finalize_kernel<<<B * N / THREADS, THREADS, 0, stream>>>(points, partial, out);
}